// Round 13
// baseline (128.621 us; speedup 1.0000x reference)
//
#include <hip/hip_runtime.h>

// PathGNNLayers: per-edge MLP + scatter-max GNN layer.
//   x:[N,32] f32, edge_index:[2,E] int32, edge_attr:[E,32] f32
//   W1:[96,64], b1:[64], W2:[64,32], b2:[32]
//   out[n] = max( x[n, -32:], max_{e: col[e]==n} MLP(x[row_e], x[col_e], ea[e]) )
//
// R13: T14 async-stage split in the fused kernel. Each thread's staging is
// self-contained (own rec load -> own gather addresses): thread (m=t&127,
// side=t>>7) stages xbf[row or col of edge m] plus its half of ea[m]. The ea
// half-row (HBM, ~900cy) and next-tile rec are prefetched one tile ahead and
// ride under the MFMA phases. 3 barriers/tile (was 4). rcsE/rcsR deleted.
// NOTE: no min-waves launch bound (R11: a VGPR cap spills weight frags).

constexpr int XD   = 32;
constexpr int HID  = 64;
constexpr int OUTD = 32;
constexpr int BM   = 128;   // edges per MFMA tile
constexpr int ASTR = 104;   // A LDS stride in bf16 units
constexpr int HSTR = 72;    // H LDS stride in bf16 units (aliased into A buffer)
constexpr int BIN_SHIFT = 5;            // 32 nodes per bin
constexpr int BINW  = 1 << BIN_SHIFT;
constexpr int BLK_E = 8192;             // edges per histogram/write chunk
constexpr int EPB   = BLK_E / 256;      // edges per thread in chunk kernels

typedef __attribute__((ext_vector_type(8)))  short    short8;
typedef __attribute__((ext_vector_type(4)))  float    f32x4;
typedef __attribute__((ext_vector_type(4)))  float    floatx4;

static __device__ __forceinline__ unsigned f2bf(float f) {
    union { float f; unsigned u; } x; x.f = f;
    unsigned r = x.u + 0x7fff + ((x.u >> 16) & 1);   // RNE; finite inputs
    return r >> 16;
}
// monotone f32<->u32 encoding: enc order == float order (finite values)
static __device__ __forceinline__ unsigned encf(float f) {
    unsigned u = __float_as_uint(f);
    return (u >> 31) ? ~u : (u | 0x80000000u);
}
static __device__ __forceinline__ float decf(unsigned k) {
    return __uint_as_float((k >> 31) ? (k & 0x7fffffffu) : ~k);
}

// ---- kernel 1: blocks [0,nblk) do the bin histogram; the rest do prep
//      (x->bf16 table + W1/W2 -> MFMA B-fragment order) ----
__global__ __launch_bounds__(256) void prep_hist(
    const float* __restrict__ x, unsigned* __restrict__ xbf,
    const float* __restrict__ W1, const float* __restrict__ W2,
    unsigned* __restrict__ w1s, unsigned* __restrict__ w2s,
    const int* __restrict__ ei, unsigned* __restrict__ cnt,
    int n_edges, int nbins, int nblk, int total8)
{
    __shared__ unsigned lh[2048];          // nbins <= 2048
    const int t = threadIdx.x;
    const int b = blockIdx.x;

    if (b < nblk) {                        // ---- histogram role
        for (int i = t; i < nbins; i += 256) lh[i] = 0u;
        __syncthreads();
        const int chunk = b * BLK_E;
#pragma unroll
        for (int i = 0; i < EPB; ++i) {
            const int e = chunk + i * 256 + t;
            if (e < n_edges)
                atomicAdd(&lh[((unsigned)ei[n_edges + e]) >> BIN_SHIFT], 1u);
        }
        __syncthreads();
        for (int i = t; i < nbins; i += 256)
            cnt[(size_t)b * nbins + i] = lh[i];
        return;
    }

    // ---- prep role
    const int i = (b - nblk) * 256 + t;

    if (i < total8) {                      // x (f32) -> xbf (bf16), 8 floats/thread
        const float4* src = reinterpret_cast<const float4*>(x) + (size_t)i * 2;
        float4 a = src[0], bb = src[1];
        uint4 o;
        o.x = f2bf(a.x)  | (f2bf(a.y)  << 16);
        o.y = f2bf(a.z)  | (f2bf(a.w)  << 16);
        o.z = f2bf(bb.x) | (f2bf(bb.y) << 16);
        o.w = f2bf(bb.z) | (f2bf(bb.w) << 16);
        reinterpret_cast<uint4*>(xbf)[i] = o;
    }

    // B-frag for tile (nt,ks): lane l holds B[k=ks*32+(l>>4)*8+j][col=nt*16+(l&15)]
    if (i < 768) {                         // W1: 4 nt x 3 ks x 64 lanes
        const int ti = i >> 6, lane = i & 63;
        const int nt = ti / 3, ks = ti % 3;
        const int col = nt * 16 + (lane & 15);
        const int k0  = ks * 32 + ((lane >> 4) << 3);
        unsigned o[4];
#pragma unroll
        for (int p = 0; p < 4; ++p)
            o[p] = f2bf(W1[(k0 + 2 * p) * HID + col]) |
                   (f2bf(W1[(k0 + 2 * p + 1) * HID + col]) << 16);
        reinterpret_cast<uint4*>(w1s)[i] = make_uint4(o[0], o[1], o[2], o[3]);
    } else if (i < 1024) {                 // W2: 2 nt x 2 ks x 64 lanes
        const int tt = i - 768;
        const int ti = tt >> 6, lane = tt & 63;
        const int nt = ti >> 1, ks = ti & 1;
        const int col = nt * 16 + (lane & 15);
        const int k0  = ks * 32 + ((lane >> 4) << 3);
        unsigned o[4];
#pragma unroll
        for (int p = 0; p < 4; ++p)
            o[p] = f2bf(W2[(k0 + 2 * p) * OUTD + col]) |
                   (f2bf(W2[(k0 + 2 * p + 1) * OUTD + col]) << 16);
        reinterpret_cast<uint4*>(w2s)[tt] = make_uint4(o[0], o[1], o[2], o[3]);
    }
}

// ---- per-bin exclusive scan over chunk counts (one block per bin) ----
__global__ __launch_bounds__(128) void bin_off(
    const unsigned* __restrict__ cnt, unsigned* __restrict__ off,
    unsigned* __restrict__ totals, int nblk, int nbins)
{
    __shared__ unsigned ts[128];           // nblk <= 128
    const int j = blockIdx.x;
    const int t = threadIdx.x;
    const unsigned d = (t < nblk) ? cnt[(size_t)t * nbins + j] : 0u;
    ts[t] = d;
    __syncthreads();
#pragma unroll
    for (int o = 1; o < 128; o <<= 1) {
        unsigned v = (t >= o) ? ts[t - o] : 0u;
        __syncthreads();
        ts[t] += v;
        __syncthreads();
    }
    if (t < nblk) off[(size_t)t * nbins + j] = ts[t] - d;   // exclusive
    if (t == 127) totals[j] = ts[127];
}

// ---- exclusive scan of totals -> base[]; base[nbins] = E (nbins <= 2048) ----
__global__ __launch_bounds__(256) void base_scan(
    const unsigned* __restrict__ totals, unsigned* __restrict__ base, int nbins)
{
    __shared__ unsigned ts[256];
    const int t = threadIdx.x;
    unsigned d[8];
    unsigned s = 0;
#pragma unroll
    for (int k = 0; k < 8; ++k) {
        const int i = t * 8 + k;
        d[k] = (i < nbins) ? totals[i] : 0u;
        s += d[k];
    }
    ts[t] = s;
    __syncthreads();
#pragma unroll
    for (int o = 1; o < 256; o <<= 1) {
        unsigned v = (t >= o) ? ts[t - o] : 0u;
        __syncthreads();
        ts[t] += v;
        __syncthreads();
    }
    unsigned run = (t == 0) ? 0u : ts[t - 1];
#pragma unroll
    for (int k = 0; k < 8; ++k) {
        const int i = t * 8 + k;
        if (i < nbins) base[i] = run;
        run += d[k];
    }
    if (t == 255) base[nbins] = run;       // grand total
}

// ---- write records; each (chunk,bin) run owned by one block ----
__global__ __launch_bounds__(256) void bin_write(
    const int* __restrict__ ei, const unsigned* __restrict__ off,
    const unsigned* __restrict__ base, uint2* __restrict__ rec,
    int n_edges, int nbins)
{
    __shared__ unsigned loff[2048];
    __shared__ unsigned lrank[2048];
    const int t = threadIdx.x;
    const int b = blockIdx.x;
    for (int i = t; i < nbins; i += 256) {
        loff[i]  = base[i] + off[(size_t)b * nbins + i];
        lrank[i] = 0u;
    }
    __syncthreads();
    const int chunk = b * BLK_E;
#pragma unroll
    for (int i = 0; i < EPB; ++i) {
        const int e = chunk + i * 256 + t;
        if (e < n_edges) {
            const unsigned row = (unsigned)ei[e];
            const unsigned col = (unsigned)ei[n_edges + e];
            const unsigned bin = col >> BIN_SHIFT;
            const unsigned r   = atomicAdd(&lrank[bin], 1u);   // LDS only
            rec[loff[bin] + r] = make_uint2((row << 16) | col, (unsigned)e);
        }
    }
}

// ---- fused: one block per 32-node bin; software-pipelined MFMA MLP tiles
//      + LDS max accumulator. ----
__global__ __launch_bounds__(256) void edge_mlp_fused(
    const unsigned* __restrict__ xbf,   // [N][16] u32 = [N][32] bf16
    const uint2*    __restrict__ rec,   // [E] {(row<<16)|col, e}, bin-grouped
    const float*    __restrict__ ea,
    const unsigned* __restrict__ w1s,   // [12][64] x 16B frags
    const unsigned* __restrict__ w2s,   // [4][64] x 16B frags
    const float*    __restrict__ b1,
    const float*    __restrict__ b2,
    const float*    __restrict__ x,
    const unsigned* __restrict__ base,  // [nbins+1]
    float*          __restrict__ out,   // [N][32] f32 (fully written here)
    int n_edges, int n_nodes)
{
    __shared__ alignas(16) unsigned short S[BM * ASTR];   // A tile; H aliased
    __shared__ unsigned accK[BINW * OUTD];                // monotone-encoded f32 max
    __shared__ unsigned rcsC[BM];                         // node id per tile row

    const int t    = threadIdx.x;
    const int lane = t & 63;
    const int wave = t >> 6;
    const int bin  = blockIdx.x;
    const int n0   = bin << BIN_SHIFT;

    const int m    = t & 127;     // my edge slot within the tile
    const int side = t >> 7;      // 0 -> x[row] + ea[0:16), 1 -> x[col] + ea[16:32)

    const unsigned sbeg = base[bin];
    const unsigned send = base[bin + 1];

    // weight fragments + biases (registers, once; L2-hot across blocks)
    short8 w1f[12];
#pragma unroll
    for (int ti = 0; ti < 12; ++ti)
        w1f[ti] = *reinterpret_cast<const short8*>(w1s + (size_t)(ti * 64 + lane) * 4);
    short8 w2f[4];
#pragma unroll
    for (int ti = 0; ti < 4; ++ti)
        w2f[ti] = *reinterpret_cast<const short8*>(w2s + (size_t)(ti * 64 + lane) * 4);
    float bb1[4];
#pragma unroll
    for (int nt = 0; nt < 4; ++nt) bb1[nt] = b1[nt * 16 + (lane & 15)];
    float bb2[2];
#pragma unroll
    for (int nt = 0; nt < 2; ++nt) bb2[nt] = b2[nt * 16 + (lane & 15)];

    // init accumulator with x residual (also covers empty nodes)
#pragma unroll
    for (int k = 0; k < (BINW * OUTD) / 256; ++k) {
        const int idx = t + k * 256;
        const int g   = n0 + (idx >> 5);
        const float r = (g < n_nodes) ? x[(size_t)g * XD + (idx & 31)] : 0.0f;
        accK[idx] = encf(r);
    }

    const int ntile = (int)(send - sbeg + BM - 1) / BM;

    // pipeline registers: my edge's metadata + prefetched ea half-row
    unsigned myE = 0, myR = 0, myC = 0;
    floatx4  eg[4];

    if (ntile > 0) {            // prologue: rec + ea prefetch for tile 0
        unsigned p = sbeg + (unsigned)m;
        if (p >= send) p = send - 1;            // duplicate pad; max-idempotent
        const uint2 q = rec[p];
        myE = q.y; myR = q.x >> 16; myC = q.x & 0xffffu;
        const floatx4* es = reinterpret_cast<const floatx4*>(
            ea + (size_t)myE * 32 + side * 16);
#pragma unroll
        for (int k = 0; k < 4; ++k) eg[k] = __builtin_nontemporal_load(es + k);
    }

    for (int tile = 0; tile < ntile; ++tile) {
        // prefetch next tile's rec (position-indexed; independent of my*)
        unsigned nE = myE, nR = myR, nC = myC;
        if (tile + 1 < ntile) {
            unsigned p = sbeg + (unsigned)(tile + 1) * BM + m;
            if (p >= send) p = send - 1;
            const uint2 q = rec[p];
            nE = q.y; nR = q.x >> 16; nC = q.x & 0xffffu;
        }

        __syncthreads();   // S free (previous tile's reads done), rcsC consumed

        // ---- write phase (tile i): xbf gather (L2) + prefetched ea regs -> S
        {
            const unsigned gid = side ? myC : myR;
            const uint4* src = reinterpret_cast<const uint4*>(xbf + (size_t)gid * 16);
            uint4 xg0 = src[0], xg1 = src[1], xg2 = src[2], xg3 = src[3];

#pragma unroll
            for (int k = 0; k < 4; ++k) {          // ea half-row, f32 -> bf16
                uint2 pk;
                pk.x = f2bf(eg[k].x) | (f2bf(eg[k].y) << 16);
                pk.y = f2bf(eg[k].z) | (f2bf(eg[k].w) << 16);
                *reinterpret_cast<uint2*>(&S[m * ASTR + 64 + side * 16 + k * 4]) = pk;
            }
            if (side == 0) rcsC[m] = myC;

            *reinterpret_cast<uint4*>(&S[m * ASTR + side * 32 +  0]) = xg0;
            *reinterpret_cast<uint4*>(&S[m * ASTR + side * 32 +  8]) = xg1;
            *reinterpret_cast<uint4*>(&S[m * ASTR + side * 32 + 16]) = xg2;
            *reinterpret_cast<uint4*>(&S[m * ASTR + side * 32 + 24]) = xg3;
        }
        __syncthreads();   // staging visible

        // ---- advance pipeline: issue ea prefetch for tile i+1 (rides under MFMA)
        myE = nE; myR = nR; myC = nC;
        if (tile + 1 < ntile) {
            const floatx4* es = reinterpret_cast<const floatx4*>(
                ea + (size_t)myE * 32 + side * 16);
#pragma unroll
            for (int k = 0; k < 4; ++k) eg[k] = __builtin_nontemporal_load(es + k);
        }

        // ---- layer 1: [128x96] @ [96x64]
        f32x4 acc1[2][4];
#pragma unroll
        for (int mi = 0; mi < 2; ++mi)
#pragma unroll
            for (int nt = 0; nt < 4; ++nt) acc1[mi][nt] = (f32x4){0.f, 0.f, 0.f, 0.f};
#pragma unroll
        for (int ks = 0; ks < 3; ++ks) {
#pragma unroll
            for (int mi = 0; mi < 2; ++mi) {
                const int mt = wave * 2 + mi;
                short8 afrag = *reinterpret_cast<const short8*>(
                    &S[(mt * 16 + (lane & 15)) * ASTR + ks * 32 + ((lane >> 4) << 3)]);
#pragma unroll
                for (int nt = 0; nt < 4; ++nt)
                    acc1[mi][nt] = __builtin_amdgcn_mfma_f32_16x16x32_bf16(
                        afrag, w1f[nt * 3 + ks], acc1[mi][nt], 0, 0, 0);
            }
        }
        __syncthreads();   // all A reads done -> S reusable for H

        // ---- bias + ReLU -> H (bf16) into S with HSTR layout.
        // H rows are WAVE-PRIVATE (wave w writes+reads rows [32w,32w+32)),
        // so no barrier needed between write and layer-2 read.
#pragma unroll
        for (int mi = 0; mi < 2; ++mi) {
            const int mt = wave * 2 + mi;
#pragma unroll
            for (int nt = 0; nt < 4; ++nt)
#pragma unroll
                for (int r = 0; r < 4; ++r) {
                    const float h = fmaxf(acc1[mi][nt][r] + bb1[nt], 0.0f);
                    S[(mt * 16 + ((lane >> 4) << 2) + r) * HSTR + nt * 16 + (lane & 15)] =
                        (unsigned short)f2bf(h);
                }
        }

        // ---- layer 2: [128x64] @ [64x32]  (reads own wave's H rows)
        f32x4 acc2[2][2];
#pragma unroll
        for (int mi = 0; mi < 2; ++mi)
#pragma unroll
            for (int nt = 0; nt < 2; ++nt) acc2[mi][nt] = (f32x4){0.f, 0.f, 0.f, 0.f};
#pragma unroll
        for (int ks = 0; ks < 2; ++ks) {
#pragma unroll
            for (int mi = 0; mi < 2; ++mi) {
                const int mt = wave * 2 + mi;
                short8 hfrag = *reinterpret_cast<const short8*>(
                    &S[(mt * 16 + (lane & 15)) * HSTR + ks * 32 + ((lane >> 4) << 3)]);
#pragma unroll
                for (int nt = 0; nt < 2; ++nt)
                    acc2[mi][nt] = __builtin_amdgcn_mfma_f32_16x16x32_bf16(
                        hfrag, w2f[nt * 2 + ks], acc2[mi][nt], 0, 0, 0);
            }
        }

        // ---- epilogue: bias + LDS atomicMax straight from MFMA regs
#pragma unroll
        for (int mi = 0; mi < 2; ++mi) {
            const int mt = wave * 2 + mi;
#pragma unroll
            for (int nt = 0; nt < 2; ++nt)
#pragma unroll
                for (int r = 0; r < 4; ++r) {
                    const int row = mt * 16 + ((lane >> 4) << 2) + r;
                    const float val = acc2[mi][nt][r] + bb2[nt];
                    const int ln = (int)rcsC[row] - n0;      // in [0,BINW)
                    atomicMax(&accK[ln * OUTD + nt * 16 + (lane & 15)], encf(val));
                }
        }
    }

    __syncthreads();
    // final: decode and store (each node written exactly once -> deterministic)
#pragma unroll
    for (int k = 0; k < (BINW * OUTD) / 256; ++k) {
        const int idx = t + k * 256;
        const int g   = n0 + (idx >> 5);
        if (g < n_nodes)
            out[(size_t)g * OUTD + (idx & 31)] = decf(accK[idx]);
    }
}

extern "C" void kernel_launch(void* const* d_in, const int* in_sizes, int n_in,
                              void* d_out, int out_size, void* d_ws, size_t ws_size,
                              hipStream_t stream)
{
    const float* x  = (const float*)d_in[0];
    const int*   ei = (const int*)  d_in[1];
    const float* ea = (const float*)d_in[2];
    const float* W1 = (const float*)d_in[3];
    const float* b1 = (const float*)d_in[4];
    const float* W2 = (const float*)d_in[5];
    const float* b2 = (const float*)d_in[6];
    float* out = (float*)d_out;

    const int n_nodes = in_sizes[0] / XD;
    const int n_edges = in_sizes[2] / 32;
    const int nbins   = (n_nodes + BINW - 1) >> BIN_SHIFT;      // 1563
    const int nblk    = (n_edges + BLK_E - 1) / BLK_E;          // 98 (<=128)

    // ws: cnt[nblk*nbins] | off[nblk*nbins] | totals[nbins] | base[nbins+1] |
    //     rec[E] uint2 | xbf[N*16 u32] | w1s | w2s
    size_t off_b = 0;
    unsigned* cnt    = (unsigned*)((char*)d_ws + off_b); off_b += (size_t)nblk * nbins * 4;
    unsigned* offm   = (unsigned*)((char*)d_ws + off_b); off_b += (size_t)nblk * nbins * 4;
    unsigned* totals = (unsigned*)((char*)d_ws + off_b); off_b += (size_t)nbins * 4;
    unsigned* basep  = (unsigned*)((char*)d_ws + off_b); off_b += (size_t)(nbins + 1) * 4;
    off_b = (off_b + 15) & ~(size_t)15;
    uint2*    rec    = (uint2*)   ((char*)d_ws + off_b); off_b += (size_t)n_edges * 8;
    unsigned* xbf    = (unsigned*)((char*)d_ws + off_b); off_b += (size_t)n_nodes * 16 * 4;
    unsigned* w1s    = (unsigned*)((char*)d_ws + off_b); off_b += 768 * 16;
    unsigned* w2s    = (unsigned*)((char*)d_ws + off_b);

    const int total8     = n_nodes * XD / 8;
    const int prep_blk   = (max(total8, 1024) + 255) / 256;

    prep_hist<<<nblk + prep_blk, 256, 0, stream>>>(
        x, xbf, W1, W2, w1s, w2s, ei, cnt, n_edges, nbins, nblk, total8);
    bin_off<<<nbins, 128, 0, stream>>>(cnt, offm, totals, nblk, nbins);
    base_scan<<<1, 256, 0, stream>>>(totals, basep, nbins);
    bin_write<<<nblk, 256, 0, stream>>>(ei, offm, basep, rec, n_edges, nbins);
    edge_mlp_fused<<<nbins, 256, 0, stream>>>(
        xbf, rec, ea, w1s, w2s, b1, b2, x, basep, out, n_edges, n_nodes);
}

// Round 14
// 92.210 us; speedup vs baseline: 1.3949x; 1.3949x over previous
//
#include <hip/hip_runtime.h>

// PathGNNLayers: per-edge MLP + scatter-max GNN layer.
//   x:[N,32] f32, edge_index:[2,E] int32, edge_attr:[E,32] f32
//   W1:[96,64], b1:[64], W2:[64,32], b2:[32]
//   out[n] = max( x[n, -32:], max_{e: col[e]==n} MLP(x[row_e], x[col_e], ea[e]) )
//
// R14: R12 base + direct-from-global MFMA A-fragments. The A-tile LDS staging
// round-trip is deleted: lane l loads its 16B x-fragment straight from the
// L2-resident xbf table (addresses via rcs LDS records) and converts its 32B
// ea fragment in registers. 2 barriers/tile (was 4), LDS 24.1KB (was 32.3).
// Traffic identical; latency chain much shorter.
// NOTE: no min-waves launch bound (R11: a VGPR cap spills weight frags).

constexpr int XD   = 32;
constexpr int HID  = 64;
constexpr int OUTD = 32;
constexpr int BM   = 128;   // edges per MFMA tile
constexpr int HSTR = 72;    // H LDS stride in bf16 units
constexpr int BIN_SHIFT = 5;            // 32 nodes per bin
constexpr int BINW  = 1 << BIN_SHIFT;
constexpr int BLK_E = 8192;             // edges per histogram/write chunk
constexpr int EPB   = BLK_E / 256;      // edges per thread in chunk kernels

typedef __attribute__((ext_vector_type(8)))  short    short8;
typedef __attribute__((ext_vector_type(4)))  float    f32x4;
typedef __attribute__((ext_vector_type(4)))  float    floatx4;

static __device__ __forceinline__ unsigned f2bf(float f) {
    union { float f; unsigned u; } x; x.f = f;
    unsigned r = x.u + 0x7fff + ((x.u >> 16) & 1);   // RNE; finite inputs
    return r >> 16;
}
// monotone f32<->u32 encoding: enc order == float order (finite values)
static __device__ __forceinline__ unsigned encf(float f) {
    unsigned u = __float_as_uint(f);
    return (u >> 31) ? ~u : (u | 0x80000000u);
}
static __device__ __forceinline__ float decf(unsigned k) {
    return __uint_as_float((k >> 31) ? (k & 0x7fffffffu) : ~k);
}

// ---- kernel 1: blocks [0,nblk) do the bin histogram; the rest do prep
//      (x->bf16 table + W1/W2 -> MFMA B-fragment order) ----
__global__ __launch_bounds__(256) void prep_hist(
    const float* __restrict__ x, unsigned* __restrict__ xbf,
    const float* __restrict__ W1, const float* __restrict__ W2,
    unsigned* __restrict__ w1s, unsigned* __restrict__ w2s,
    const int* __restrict__ ei, unsigned* __restrict__ cnt,
    int n_edges, int nbins, int nblk, int total8)
{
    __shared__ unsigned lh[2048];          // nbins <= 2048
    const int t = threadIdx.x;
    const int b = blockIdx.x;

    if (b < nblk) {                        // ---- histogram role
        for (int i = t; i < nbins; i += 256) lh[i] = 0u;
        __syncthreads();
        const int chunk = b * BLK_E;
#pragma unroll
        for (int i = 0; i < EPB; ++i) {
            const int e = chunk + i * 256 + t;
            if (e < n_edges)
                atomicAdd(&lh[((unsigned)ei[n_edges + e]) >> BIN_SHIFT], 1u);
        }
        __syncthreads();
        for (int i = t; i < nbins; i += 256)
            cnt[(size_t)b * nbins + i] = lh[i];
        return;
    }

    // ---- prep role
    const int i = (b - nblk) * 256 + t;

    if (i < total8) {                      // x (f32) -> xbf (bf16), 8 floats/thread
        const float4* src = reinterpret_cast<const float4*>(x) + (size_t)i * 2;
        float4 a = src[0], bb = src[1];
        uint4 o;
        o.x = f2bf(a.x)  | (f2bf(a.y)  << 16);
        o.y = f2bf(a.z)  | (f2bf(a.w)  << 16);
        o.z = f2bf(bb.x) | (f2bf(bb.y) << 16);
        o.w = f2bf(bb.z) | (f2bf(bb.w) << 16);
        reinterpret_cast<uint4*>(xbf)[i] = o;
    }

    // B-frag for tile (nt,ks): lane l holds B[k=ks*32+(l>>4)*8+j][col=nt*16+(l&15)]
    if (i < 768) {                         // W1: 4 nt x 3 ks x 64 lanes
        const int ti = i >> 6, lane = i & 63;
        const int nt = ti / 3, ks = ti % 3;
        const int col = nt * 16 + (lane & 15);
        const int k0  = ks * 32 + ((lane >> 4) << 3);
        unsigned o[4];
#pragma unroll
        for (int p = 0; p < 4; ++p)
            o[p] = f2bf(W1[(k0 + 2 * p) * HID + col]) |
                   (f2bf(W1[(k0 + 2 * p + 1) * HID + col]) << 16);
        reinterpret_cast<uint4*>(w1s)[i] = make_uint4(o[0], o[1], o[2], o[3]);
    } else if (i < 1024) {                 // W2: 2 nt x 2 ks x 64 lanes
        const int tt = i - 768;
        const int ti = tt >> 6, lane = tt & 63;
        const int nt = ti >> 1, ks = ti & 1;
        const int col = nt * 16 + (lane & 15);
        const int k0  = ks * 32 + ((lane >> 4) << 3);
        unsigned o[4];
#pragma unroll
        for (int p = 0; p < 4; ++p)
            o[p] = f2bf(W2[(k0 + 2 * p) * OUTD + col]) |
                   (f2bf(W2[(k0 + 2 * p + 1) * OUTD + col]) << 16);
        reinterpret_cast<uint4*>(w2s)[tt] = make_uint4(o[0], o[1], o[2], o[3]);
    }
}

// ---- per-bin exclusive scan over chunk counts (one block per bin) ----
__global__ __launch_bounds__(128) void bin_off(
    const unsigned* __restrict__ cnt, unsigned* __restrict__ off,
    unsigned* __restrict__ totals, int nblk, int nbins)
{
    __shared__ unsigned ts[128];           // nblk <= 128
    const int j = blockIdx.x;
    const int t = threadIdx.x;
    const unsigned d = (t < nblk) ? cnt[(size_t)t * nbins + j] : 0u;
    ts[t] = d;
    __syncthreads();
#pragma unroll
    for (int o = 1; o < 128; o <<= 1) {
        unsigned v = (t >= o) ? ts[t - o] : 0u;
        __syncthreads();
        ts[t] += v;
        __syncthreads();
    }
    if (t < nblk) off[(size_t)t * nbins + j] = ts[t] - d;   // exclusive
    if (t == 127) totals[j] = ts[127];
}

// ---- exclusive scan of totals -> base[]; base[nbins] = E (nbins <= 2048) ----
__global__ __launch_bounds__(256) void base_scan(
    const unsigned* __restrict__ totals, unsigned* __restrict__ base, int nbins)
{
    __shared__ unsigned ts[256];
    const int t = threadIdx.x;
    unsigned d[8];
    unsigned s = 0;
#pragma unroll
    for (int k = 0; k < 8; ++k) {
        const int i = t * 8 + k;
        d[k] = (i < nbins) ? totals[i] : 0u;
        s += d[k];
    }
    ts[t] = s;
    __syncthreads();
#pragma unroll
    for (int o = 1; o < 256; o <<= 1) {
        unsigned v = (t >= o) ? ts[t - o] : 0u;
        __syncthreads();
        ts[t] += v;
        __syncthreads();
    }
    unsigned run = (t == 0) ? 0u : ts[t - 1];
#pragma unroll
    for (int k = 0; k < 8; ++k) {
        const int i = t * 8 + k;
        if (i < nbins) base[i] = run;
        run += d[k];
    }
    if (t == 255) base[nbins] = run;       // grand total
}

// ---- write records; each (chunk,bin) run owned by one block ----
__global__ __launch_bounds__(256) void bin_write(
    const int* __restrict__ ei, const unsigned* __restrict__ off,
    const unsigned* __restrict__ base, uint2* __restrict__ rec,
    int n_edges, int nbins)
{
    __shared__ unsigned loff[2048];
    __shared__ unsigned lrank[2048];
    const int t = threadIdx.x;
    const int b = blockIdx.x;
    for (int i = t; i < nbins; i += 256) {
        loff[i]  = base[i] + off[(size_t)b * nbins + i];
        lrank[i] = 0u;
    }
    __syncthreads();
    const int chunk = b * BLK_E;
#pragma unroll
    for (int i = 0; i < EPB; ++i) {
        const int e = chunk + i * 256 + t;
        if (e < n_edges) {
            const unsigned row = (unsigned)ei[e];
            const unsigned col = (unsigned)ei[n_edges + e];
            const unsigned bin = col >> BIN_SHIFT;
            const unsigned r   = atomicAdd(&lrank[bin], 1u);   // LDS only
            rec[loff[bin] + r] = make_uint2((row << 16) | col, (unsigned)e);
        }
    }
}

// ---- fused: one block per 32-node bin; MFMA MLP with direct-global A-frags
//      + LDS max accumulator. ----
__global__ __launch_bounds__(256) void edge_mlp_fused(
    const unsigned* __restrict__ xbf,   // [N][16] u32 = [N][32] bf16
    const uint2*    __restrict__ rec,   // [E] {(row<<16)|col, e}, bin-grouped
    const float*    __restrict__ ea,
    const unsigned* __restrict__ w1s,   // [12][64] x 16B frags
    const unsigned* __restrict__ w2s,   // [4][64] x 16B frags
    const float*    __restrict__ b1,
    const float*    __restrict__ b2,
    const float*    __restrict__ x,
    const unsigned* __restrict__ base,  // [nbins+1]
    float*          __restrict__ out,   // [N][32] f32 (fully written here)
    int n_edges, int n_nodes)
{
    __shared__ alignas(16) unsigned short Hlds[BM * HSTR];  // 18432 B
    __shared__ unsigned accK[BINW * OUTD];                  // 4096 B
    __shared__ unsigned rcsE[BM];
    __shared__ unsigned rcsR[BM];
    __shared__ unsigned rcsC[BM];

    const int t    = threadIdx.x;
    const int lane = t & 63;
    const int wave = t >> 6;
    const int bin  = blockIdx.x;
    const int n0   = bin << BIN_SHIFT;

    const unsigned sbeg = base[bin];
    const unsigned send = base[bin + 1];

    // weight fragments + biases (registers, once; L2-hot across blocks)
    short8 w1f[12];
#pragma unroll
    for (int ti = 0; ti < 12; ++ti)
        w1f[ti] = *reinterpret_cast<const short8*>(w1s + (size_t)(ti * 64 + lane) * 4);
    short8 w2f[4];
#pragma unroll
    for (int ti = 0; ti < 4; ++ti)
        w2f[ti] = *reinterpret_cast<const short8*>(w2s + (size_t)(ti * 64 + lane) * 4);
    float bb1[4];
#pragma unroll
    for (int nt = 0; nt < 4; ++nt) bb1[nt] = b1[nt * 16 + (lane & 15)];
    float bb2[2];
#pragma unroll
    for (int nt = 0; nt < 2; ++nt) bb2[nt] = b2[nt * 16 + (lane & 15)];

    // init accumulator with x residual (also covers empty nodes)
#pragma unroll
    for (int k = 0; k < (BINW * OUTD) / 256; ++k) {
        const int idx = t + k * 256;
        const int g   = n0 + (idx >> 5);
        const float r = (g < n_nodes) ? x[(size_t)g * XD + (idx & 31)] : 0.0f;
        accK[idx] = encf(r);
    }

    const int ntile = (int)(send - sbeg + BM - 1) / BM;
    const int koff  = lane >> 4;          // 0..3: which 16B/32B slice of the row

    for (int tile = 0; tile < ntile; ++tile) {
        __syncthreads();   // all reads of rcs from previous tile done

        if (t < BM) {
            unsigned p = sbeg + (unsigned)tile * BM + t;
            if (p >= send) p = send - 1;            // duplicate pad; max-idempotent
            const uint2 q = rec[p];
            rcsE[t] = q.y; rcsR[t] = q.x >> 16; rcsC[t] = q.x & 0xffffu;
        }
        __syncthreads();   // rcs visible

        // ---- layer 1: [128x96] @ [96x64], A-frags direct from global
        f32x4 acc1[2][4];
#pragma unroll
        for (int mi = 0; mi < 2; ++mi)
#pragma unroll
            for (int nt = 0; nt < 4; ++nt) acc1[mi][nt] = (f32x4){0.f, 0.f, 0.f, 0.f};

#pragma unroll
        for (int mi = 0; mi < 2; ++mi) {
            const int row16 = (wave * 2 + mi) * 16 + (lane & 15);
            const unsigned idR = rcsR[row16];
            const unsigned idC = rcsC[row16];
            const unsigned eid = rcsE[row16];

            // ks=0: x[row] k 0..31 ; ks=1: x[col] k 32..63  (16B bf16 each)
            const short8 aR = *reinterpret_cast<const short8*>(
                xbf + (size_t)idR * 16 + koff * 4);
            const short8 aC = *reinterpret_cast<const short8*>(
                xbf + (size_t)idC * 16 + koff * 4);
            // ks=2: ea k 64..95 (32B f32 -> 8 bf16 in-register)
            const floatx4* ep = reinterpret_cast<const floatx4*>(
                ea + (size_t)eid * 32 + koff * 8);
            const floatx4 e0 = ep[0], e1 = ep[1];
            union { uint4 u; short8 s; } ae;
            ae.u.x = f2bf(e0.x) | (f2bf(e0.y) << 16);
            ae.u.y = f2bf(e0.z) | (f2bf(e0.w) << 16);
            ae.u.z = f2bf(e1.x) | (f2bf(e1.y) << 16);
            ae.u.w = f2bf(e1.z) | (f2bf(e1.w) << 16);

#pragma unroll
            for (int nt = 0; nt < 4; ++nt) {
                acc1[mi][nt] = __builtin_amdgcn_mfma_f32_16x16x32_bf16(
                    aR, w1f[nt * 3 + 0], acc1[mi][nt], 0, 0, 0);
                acc1[mi][nt] = __builtin_amdgcn_mfma_f32_16x16x32_bf16(
                    aC, w1f[nt * 3 + 1], acc1[mi][nt], 0, 0, 0);
                acc1[mi][nt] = __builtin_amdgcn_mfma_f32_16x16x32_bf16(
                    ae.s, w1f[nt * 3 + 2], acc1[mi][nt], 0, 0, 0);
            }
        }

        // ---- bias + ReLU -> H (bf16, LDS). C layout: col=lane&15, row=(lane>>4)*4+r.
        // H rows are WAVE-PRIVATE (wave w writes+reads rows [32w,32w+32)),
        // so no barrier needed between write and layer-2 read.
#pragma unroll
        for (int mi = 0; mi < 2; ++mi) {
            const int mt = wave * 2 + mi;
#pragma unroll
            for (int nt = 0; nt < 4; ++nt)
#pragma unroll
                for (int r = 0; r < 4; ++r) {
                    const float h = fmaxf(acc1[mi][nt][r] + bb1[nt], 0.0f);
                    Hlds[(mt * 16 + ((lane >> 4) << 2) + r) * HSTR + nt * 16 + (lane & 15)] =
                        (unsigned short)f2bf(h);
                }
        }

        // ---- layer 2: [128x64] @ [64x32]  (reads own wave's H rows)
        f32x4 acc2[2][2];
#pragma unroll
        for (int mi = 0; mi < 2; ++mi)
#pragma unroll
            for (int nt = 0; nt < 2; ++nt) acc2[mi][nt] = (f32x4){0.f, 0.f, 0.f, 0.f};
#pragma unroll
        for (int ks = 0; ks < 2; ++ks) {
#pragma unroll
            for (int mi = 0; mi < 2; ++mi) {
                const int mt = wave * 2 + mi;
                short8 hfrag = *reinterpret_cast<const short8*>(
                    &Hlds[(mt * 16 + (lane & 15)) * HSTR + ks * 32 + ((lane >> 4) << 3)]);
#pragma unroll
                for (int nt = 0; nt < 2; ++nt)
                    acc2[mi][nt] = __builtin_amdgcn_mfma_f32_16x16x32_bf16(
                        hfrag, w2f[nt * 2 + ks], acc2[mi][nt], 0, 0, 0);
            }
        }

        // ---- epilogue: bias + LDS atomicMax straight from MFMA regs
#pragma unroll
        for (int mi = 0; mi < 2; ++mi) {
            const int mt = wave * 2 + mi;
#pragma unroll
            for (int nt = 0; nt < 2; ++nt)
#pragma unroll
                for (int r = 0; r < 4; ++r) {
                    const int row = mt * 16 + ((lane >> 4) << 2) + r;
                    const float val = acc2[mi][nt][r] + bb2[nt];
                    const int ln = (int)rcsC[row] - n0;      // in [0,BINW)
                    atomicMax(&accK[ln * OUTD + nt * 16 + (lane & 15)], encf(val));
                }
        }
    }

    __syncthreads();
    // final: decode and store (each node written exactly once -> deterministic)
#pragma unroll
    for (int k = 0; k < (BINW * OUTD) / 256; ++k) {
        const int idx = t + k * 256;
        const int g   = n0 + (idx >> 5);
        if (g < n_nodes)
            out[(size_t)g * OUTD + (idx & 31)] = decf(accK[idx]);
    }
}

extern "C" void kernel_launch(void* const* d_in, const int* in_sizes, int n_in,
                              void* d_out, int out_size, void* d_ws, size_t ws_size,
                              hipStream_t stream)
{
    const float* x  = (const float*)d_in[0];
    const int*   ei = (const int*)  d_in[1];
    const float* ea = (const float*)d_in[2];
    const float* W1 = (const float*)d_in[3];
    const float* b1 = (const float*)d_in[4];
    const float* W2 = (const float*)d_in[5];
    const float* b2 = (const float*)d_in[6];
    float* out = (float*)d_out;

    const int n_nodes = in_sizes[0] / XD;
    const int n_edges = in_sizes[2] / 32;
    const int nbins   = (n_nodes + BINW - 1) >> BIN_SHIFT;      // 1563
    const int nblk    = (n_edges + BLK_E - 1) / BLK_E;          // 98 (<=128)

    // ws: cnt[nblk*nbins] | off[nblk*nbins] | totals[nbins] | base[nbins+1] |
    //     rec[E] uint2 | xbf[N*16 u32] | w1s | w2s
    size_t off_b = 0;
    unsigned* cnt    = (unsigned*)((char*)d_ws + off_b); off_b += (size_t)nblk * nbins * 4;
    unsigned* offm   = (unsigned*)((char*)d_ws + off_b); off_b += (size_t)nblk * nbins * 4;
    unsigned* totals = (unsigned*)((char*)d_ws + off_b); off_b += (size_t)nbins * 4;
    unsigned* basep  = (unsigned*)((char*)d_ws + off_b); off_b += (size_t)(nbins + 1) * 4;
    off_b = (off_b + 15) & ~(size_t)15;
    uint2*    rec    = (uint2*)   ((char*)d_ws + off_b); off_b += (size_t)n_edges * 8;
    unsigned* xbf    = (unsigned*)((char*)d_ws + off_b); off_b += (size_t)n_nodes * 16 * 4;
    unsigned* w1s    = (unsigned*)((char*)d_ws + off_b); off_b += 768 * 16;
    unsigned* w2s    = (unsigned*)((char*)d_ws + off_b);

    const int total8     = n_nodes * XD / 8;
    const int prep_blk   = (max(total8, 1024) + 255) / 256;

    prep_hist<<<nblk + prep_blk, 256, 0, stream>>>(
        x, xbf, W1, W2, w1s, w2s, ei, cnt, n_edges, nbins, nblk, total8);
    bin_off<<<nbins, 128, 0, stream>>>(cnt, offm, totals, nblk, nbins);
    base_scan<<<1, 256, 0, stream>>>(totals, basep, nbins);
    bin_write<<<nblk, 256, 0, stream>>>(ei, offm, basep, rec, n_edges, nbins);
    edge_mlp_fused<<<nbins, 256, 0, stream>>>(
        xbf, rec, ea, w1s, w2s, b1, b2, x, basep, out, n_edges, n_nodes);
}